// Round 4
// baseline (681.252 us; speedup 1.0000x reference)
//
#include <hip/hip_runtime.h>
#include <hip/hip_bf16.h>

// ============================================================
// 2-layer GCN: per layer
//   g = (X @ W) * dinv[row]          (dense fp32 GEMM, VALU)
//   out_i = relu(dinv_i * (sum_{e:dst=i} g[src_e] + g_i) + b)
// Aggregation via per-call CSR build (no feature atomics).
// Output is fp32 (reference output dtype is float32; confirmed via
// round-0 threshold forensics: no bf16 floor applied => _any_bf16 False).
// ============================================================

// ---------- degree histogram over dst ----------
__global__ void hist_kernel(const int* __restrict__ dst, int* __restrict__ deg, int E) {
    int stride = gridDim.x * blockDim.x;
    for (int i = blockIdx.x * blockDim.x + threadIdx.x; i < E; i += stride)
        atomicAdd(&deg[dst[i]], 1);
}

// ---------- single-block scan (shuffle-based, 2 barriers/chunk) ----------
// offs = exclusive scan of deg; dinv = 1/sqrt(deg+1)
__global__ __launch_bounds__(1024) void scan_dinv_kernel(const int* __restrict__ deg,
        int* __restrict__ offs, float* __restrict__ dinv, int n) {
    __shared__ int wsum[16];
    int tid = threadIdx.x;
    int wave = tid >> 6, lane = tid & 63;
    int sbase = 0;
    const int CHUNK = 4096;                    // 1024 threads x 4 elems
    for (int base = 0; base < n; base += CHUNK) {
        int i0 = base + tid * 4;
        int v0 = 0, v1 = 0, v2 = 0, v3 = 0;
        if (i0 + 3 < n) {
            int4 v = *(const int4*)(deg + i0);
            v0 = v.x; v1 = v.y; v2 = v.z; v3 = v.w;
        } else {
            if (i0 + 0 < n) v0 = deg[i0 + 0];
            if (i0 + 1 < n) v1 = deg[i0 + 1];
            if (i0 + 2 < n) v2 = deg[i0 + 2];
            if (i0 + 3 < n) v3 = deg[i0 + 3];
        }
        int s = v0 + v1 + v2 + v3;
        int x = s;                              // inclusive wave scan via shuffles
        #pragma unroll
        for (int off = 1; off < 64; off <<= 1) {
            int y = __shfl_up(x, off, 64);
            if (lane >= off) x += y;
        }
        if (lane == 63) wsum[wave] = x;
        __syncthreads();
        int wbase = 0, tot = 0;
        #pragma unroll
        for (int w = 0; w < 16; ++w) {
            int t = wsum[w];
            if (w < wave) wbase += t;
            tot += t;
        }
        int ex = sbase + wbase + (x - s);       // exclusive prefix of this thread's 4
        if (i0 + 0 < n) { offs[i0 + 0] = ex;                dinv[i0 + 0] = 1.0f / sqrtf((float)v0 + 1.0f); }
        if (i0 + 1 < n) { offs[i0 + 1] = ex + v0;           dinv[i0 + 1] = 1.0f / sqrtf((float)v1 + 1.0f); }
        if (i0 + 2 < n) { offs[i0 + 2] = ex + v0 + v1;      dinv[i0 + 2] = 1.0f / sqrtf((float)v2 + 1.0f); }
        if (i0 + 3 < n) { offs[i0 + 3] = ex + v0 + v1 + v2; dinv[i0 + 3] = 1.0f / sqrtf((float)v3 + 1.0f); }
        sbase += tot;
        __syncthreads();                        // wsum reuse next chunk
    }
    if (tid == 0) offs[n] = sbase;
}

// ---------- CSR bucket fill ----------
__global__ void fill_kernel(const int* __restrict__ src, const int* __restrict__ dst,
        const int* __restrict__ offs, int* __restrict__ cursor,
        int* __restrict__ csr, int E) {
    int stride = gridDim.x * blockDim.x;
    for (int i = blockIdx.x * blockDim.x + threadIdx.x; i < E; i += stride) {
        int d = dst[i];
        int pos = offs[d] + atomicAdd(&cursor[d], 1);
        csr[pos] = src[i];
    }
}

// ---------- fp32 tiled GEMM with row scaling: G[m,n] = dinv[m] * sum_k X[m,k] W[k,n] ----------
template <int K, int N, int RPT>
__global__ __launch_bounds__(256) void gemm_scale_kernel(const float* __restrict__ X,
        const float* __restrict__ W, const float* __restrict__ dinv,
        float* __restrict__ G, int M) {
    constexpr int CPT = 8;            // cols per thread
    constexpr int CG  = N / CPT;      // col groups (16 for N=128, 8 for N=64)
    constexpr int RG  = 256 / CG;     // row groups
    constexpr int BM  = RG * RPT;     // 64 for both configs
    constexpr int BK  = 16;
    static_assert(BM == 64, "tile geometry");
    __shared__ float xs[BK][BM];      // transposed X tile
    __shared__ float ws[BK][N];

    int tid = threadIdx.x;
    int cg = tid % CG, rg = tid / CG;
    int c0 = cg * CPT, r0 = rg * RPT;
    int brow = blockIdx.x * BM;

    float acc[RPT][CPT] = {};

    for (int k0 = 0; k0 < K; k0 += BK) {
        // stage X tile (transposed): 64 rows x 16 k, float4 per thread along k
        {
            int r = tid >> 2;
            int q = tid & 3;
            int row = brow + r;
            if (row >= M) row = M - 1;                 // clamp (stores are guarded)
            const float4 xv = *(const float4*)(X + (size_t)row * K + k0 + q * 4);
            xs[q * 4 + 0][r] = xv.x;
            xs[q * 4 + 1][r] = xv.y;
            xs[q * 4 + 2][r] = xv.z;
            xs[q * 4 + 3][r] = xv.w;
        }
        // stage W tile: BK x N, float4 coalesced
        {
            constexpr int NF4  = N / 4;
            constexpr int TOT4 = BK * NF4;
            #pragma unroll
            for (int t = 0; t < TOT4 / 256; ++t) {
                int idx = tid + t * 256;
                int kk = idx / NF4, n4 = idx % NF4;
                *(float4*)&ws[kk][n4 * 4] =
                    *(const float4*)(W + (size_t)(k0 + kk) * N + n4 * 4);
            }
        }
        __syncthreads();
        #pragma unroll
        for (int k = 0; k < BK; ++k) {
            float a[RPT], b[CPT];
            #pragma unroll
            for (int r = 0; r < RPT; ++r) a[r] = xs[k][r0 + r];
            #pragma unroll
            for (int c = 0; c < CPT; ++c) b[c] = ws[k][c0 + c];
            #pragma unroll
            for (int r = 0; r < RPT; ++r)
                #pragma unroll
                for (int c = 0; c < CPT; ++c)
                    acc[r][c] = fmaf(a[r], b[c], acc[r][c]);
        }
        __syncthreads();
    }

    #pragma unroll
    for (int r = 0; r < RPT; ++r) {
        int row = brow + r0 + r;
        if (row < M) {
            float s = dinv[row];
            #pragma unroll
            for (int c = 0; c < CPT; c += 4) {
                float4 v;
                v.x = acc[r][c + 0] * s;
                v.y = acc[r][c + 1] * s;
                v.z = acc[r][c + 2] * s;
                v.w = acc[r][c + 3] * s;
                *(float4*)(G + (size_t)row * N + c0 + c) = v;
            }
        }
    }
}

// ---------- per-node gather aggregation: one wave per node, fp32 out ----------
template <int F>
__global__ __launch_bounds__(256) void aggregate_kernel(const float* __restrict__ G,
        const int* __restrict__ csr, const int* __restrict__ offs,
        const float* __restrict__ dinv, const float* __restrict__ bias,
        float* __restrict__ out, int n) {
    int wave = threadIdx.x >> 6;
    int lane = threadIdx.x & 63;
    int node = blockIdx.x * 4 + wave;
    if (node >= n) return;
    int beg = offs[node], end = offs[node + 1];

    if constexpr (F == 128) {
        float2 acc = ((const float2*)(G + (size_t)node * F))[lane];  // self loop
        int e = beg;
        for (; e + 2 <= end; e += 2) {          // 2 independent row loads in flight
            int s0 = csr[e], s1 = csr[e + 1];
            float2 v0 = ((const float2*)(G + (size_t)s0 * F))[lane];
            float2 v1 = ((const float2*)(G + (size_t)s1 * F))[lane];
            acc.x += v0.x + v1.x;
            acc.y += v0.y + v1.y;
        }
        if (e < end) {
            float2 v0 = ((const float2*)(G + (size_t)csr[e] * F))[lane];
            acc.x += v0.x;
            acc.y += v0.y;
        }
        float di = dinv[node];
        float2 r;
        r.x = fmaxf(fmaf(acc.x, di, bias[lane * 2 + 0]), 0.0f);
        r.y = fmaxf(fmaf(acc.y, di, bias[lane * 2 + 1]), 0.0f);
        ((float2*)(out + (size_t)node * F))[lane] = r;
    } else {
        float acc = G[(size_t)node * F + lane];  // self loop
        int e = beg;
        for (; e + 2 <= end; e += 2) {
            int s0 = csr[e], s1 = csr[e + 1];
            acc += G[(size_t)s0 * F + lane] + G[(size_t)s1 * F + lane];
        }
        if (e < end) acc += G[(size_t)csr[e] * F + lane];
        float di = dinv[node];
        out[(size_t)node * F + lane] = fmaxf(fmaf(acc, di, bias[lane]), 0.0f);
    }
}

extern "C" void kernel_launch(void* const* d_in, const int* in_sizes, int n_in,
                              void* d_out, int out_size, void* d_ws, size_t ws_size,
                              hipStream_t stream) {
    const float* x  = (const float*)d_in[0];
    const float* W1 = (const float*)d_in[1];
    const float* b1 = (const float*)d_in[2];
    const float* W2 = (const float*)d_in[3];
    const float* b2 = (const float*)d_in[4];
    const int* edge = (const int*)d_in[5];

    const int IN = 256, H1 = 128;
    const int E = in_sizes[5] / 2;
    const int N = in_sizes[0] / IN;
    const int* srcp = edge;
    const int* dstp = edge + E;

    // workspace layout (g2 aliases g1: g1 dead after aggregate1)
    char* ws = (char*)d_ws;
    auto alignup = [](size_t v) { return (v + 255) & ~(size_t)255; };
    size_t off = 0;
    size_t degSz = alignup((size_t)N * 4);
    int*   deg    = (int*)(ws + off);   off += degSz;
    int*   cursor = (int*)(ws + off);   off += degSz;
    int*   offs   = (int*)(ws + off);   off += alignup(((size_t)N + 1) * 4);
    float* dinv   = (float*)(ws + off); off += degSz;
    int*   csr    = (int*)(ws + off);   off += alignup((size_t)E * 4);
    float* g1     = (float*)(ws + off); off += alignup((size_t)N * H1 * 4);
    float* h1     = (float*)(ws + off); off += alignup((size_t)N * H1 * 4);
    float* g2     = g1;

    hipMemsetAsync(deg, 0, 2 * degSz, stream);   // deg + cursor contiguous

    int egrid = (E + 255) / 256;
    if (egrid > 2048) egrid = 2048;
    hist_kernel<<<egrid, 256, 0, stream>>>(dstp, deg, E);
    scan_dinv_kernel<<<1, 1024, 0, stream>>>(deg, offs, dinv, N);
    fill_kernel<<<egrid, 256, 0, stream>>>(srcp, dstp, offs, cursor, csr, E);

    int mgrid = (N + 63) / 64;
    int agrid = (N + 3) / 4;

    // layer 1: g1 = (x @ W1) * dinv ; h1 = relu(Â-agg + b1)
    gemm_scale_kernel<256, 128, 4><<<mgrid, 256, 0, stream>>>(x, W1, dinv, g1, N);
    aggregate_kernel<128><<<agrid, 256, 0, stream>>>(g1, csr, offs, dinv, b1, h1, N);
    // layer 2: g2 = (h1 @ W2) * dinv ; out = relu(Â-agg + b2)
    gemm_scale_kernel<128, 64, 2><<<mgrid, 256, 0, stream>>>(h1, W2, dinv, g2, N);
    aggregate_kernel<64><<<agrid, 256, 0, stream>>>(g2, csr, offs, dinv, b2,
                                                    (float*)d_out, N);
}

// Round 5
// 556.035 us; speedup vs baseline: 1.2252x; 1.2252x over previous
//
#include <hip/hip_runtime.h>
#include <hip/hip_bf16.h>

// ============================================================
// 2-layer GCN. Per layer:
//   g = (X @ W) * dinv[row]   (fp32 VALU GEMM, bf16 packed output)
//   out_i = relu(dinv_i * (sum_{e:dst=i} g[src_e] + g_i) + b)
// Gather sources (g1,g2) stored bf16 (RNE), accumulation fp32.
// CSR built per call; parallel 3-kernel scan; output fp32.
// ============================================================

__device__ inline float bflo(unsigned u) { return __uint_as_float(u << 16); }
__device__ inline float bfhi(unsigned u) { return __uint_as_float(u & 0xffff0000u); }
__device__ inline unsigned pack_bf16_2(float lo, float hi) {
    unsigned a = __float_as_uint(lo), b = __float_as_uint(hi);
    a = (a + 0x7fff + ((a >> 16) & 1)) >> 16;          // RNE
    b = (b + 0x7fff + ((b >> 16) & 1)) >> 16;
    return a | (b << 16);
}

// ---------- degree histogram over dst ----------
__global__ void hist_kernel(const int* __restrict__ dst, int* __restrict__ deg, int E) {
    int stride = gridDim.x * blockDim.x;
    for (int i = blockIdx.x * blockDim.x + threadIdx.x; i < E; i += stride)
        atomicAdd(&deg[dst[i]], 1);
}

// ---------- scan pass 1: per-4096-block sums; also dinv = 1/sqrt(deg+1) ----------
__global__ __launch_bounds__(1024) void scan_partial_kernel(const int* __restrict__ deg,
        int* __restrict__ psum, float* __restrict__ dinv, int n) {
    __shared__ int wsum[16];
    int tid = threadIdx.x, wave = tid >> 6, lane = tid & 63;
    int i0 = blockIdx.x * 4096 + tid * 4;
    int v0 = 0, v1 = 0, v2 = 0, v3 = 0;
    if (i0 + 3 < n) {
        int4 v = *(const int4*)(deg + i0);
        v0 = v.x; v1 = v.y; v2 = v.z; v3 = v.w;
    } else {
        if (i0 + 0 < n) v0 = deg[i0 + 0];
        if (i0 + 1 < n) v1 = deg[i0 + 1];
        if (i0 + 2 < n) v2 = deg[i0 + 2];
        if (i0 + 3 < n) v3 = deg[i0 + 3];
    }
    if (i0 + 0 < n) dinv[i0 + 0] = 1.0f / sqrtf((float)v0 + 1.0f);
    if (i0 + 1 < n) dinv[i0 + 1] = 1.0f / sqrtf((float)v1 + 1.0f);
    if (i0 + 2 < n) dinv[i0 + 2] = 1.0f / sqrtf((float)v2 + 1.0f);
    if (i0 + 3 < n) dinv[i0 + 3] = 1.0f / sqrtf((float)v3 + 1.0f);
    int s = v0 + v1 + v2 + v3;
    #pragma unroll
    for (int off = 1; off < 64; off <<= 1) s += __shfl_xor(s, off, 64);
    if (lane == 0) wsum[wave] = s;
    __syncthreads();
    if (tid == 0) {
        int t = 0;
        #pragma unroll
        for (int w = 0; w < 16; ++w) t += wsum[w];
        psum[blockIdx.x] = t;
    }
}

// ---------- scan pass 2: exclusive scan of <=64 block sums; offs[n] = total ----------
__global__ void scan_base_kernel(int* __restrict__ psum, int* __restrict__ offs,
                                 int nb, int n) {
    int lane = threadIdx.x;
    int v = (lane < nb) ? psum[lane] : 0;
    int x = v;
    #pragma unroll
    for (int off = 1; off < 64; off <<= 1) {
        int y = __shfl_up(x, off, 64);
        if (lane >= off) x += y;
    }
    if (lane < nb) psum[lane] = x - v;   // exclusive base per block
    if (lane == 63) offs[n] = x;         // grand total
}

// ---------- scan pass 3: local scan + base -> offs ----------
__global__ __launch_bounds__(1024) void scan_local_kernel(const int* __restrict__ deg,
        const int* __restrict__ psum, int* __restrict__ offs, int n) {
    __shared__ int wsum[16];
    int tid = threadIdx.x, wave = tid >> 6, lane = tid & 63;
    int i0 = blockIdx.x * 4096 + tid * 4;
    int v0 = 0, v1 = 0, v2 = 0, v3 = 0;
    if (i0 + 3 < n) {
        int4 v = *(const int4*)(deg + i0);
        v0 = v.x; v1 = v.y; v2 = v.z; v3 = v.w;
    } else {
        if (i0 + 0 < n) v0 = deg[i0 + 0];
        if (i0 + 1 < n) v1 = deg[i0 + 1];
        if (i0 + 2 < n) v2 = deg[i0 + 2];
        if (i0 + 3 < n) v3 = deg[i0 + 3];
    }
    int s = v0 + v1 + v2 + v3;
    int x = s;
    #pragma unroll
    for (int off = 1; off < 64; off <<= 1) {
        int y = __shfl_up(x, off, 64);
        if (lane >= off) x += y;
    }
    if (lane == 63) wsum[wave] = x;
    __syncthreads();
    int wbase = 0;
    #pragma unroll
    for (int w = 0; w < 16; ++w)
        if (w < wave) wbase += wsum[w];
    int ex = psum[blockIdx.x] + wbase + (x - s);
    if (i0 + 0 < n) offs[i0 + 0] = ex;
    if (i0 + 1 < n) offs[i0 + 1] = ex + v0;
    if (i0 + 2 < n) offs[i0 + 2] = ex + v0 + v1;
    if (i0 + 3 < n) offs[i0 + 3] = ex + v0 + v1 + v2;
}

// ---------- CSR bucket fill ----------
__global__ void fill_kernel(const int* __restrict__ src, const int* __restrict__ dst,
        const int* __restrict__ offs, int* __restrict__ cursor,
        int* __restrict__ csr, int E) {
    int stride = gridDim.x * blockDim.x;
    for (int i = blockIdx.x * blockDim.x + threadIdx.x; i < E; i += stride) {
        int d = dst[i];
        int pos = offs[d] + atomicAdd(&cursor[d], 1);
        csr[pos] = src[i];
    }
}

// ---------- fp32 GEMM, row-scaled, packed-bf16 output ----------
// Gp[m, n/2] uints: G[m,n] = dinv[m] * sum_k X[m,k] W[k,n], packed (n, n+1)
template <int K, int N, int RPT>
__global__ __launch_bounds__(256) void gemm_scale_kernel(const float* __restrict__ X,
        const float* __restrict__ W, const float* __restrict__ dinv,
        unsigned* __restrict__ Gp, int M) {
    constexpr int CPT = 8;
    constexpr int CG  = N / CPT;
    constexpr int RG  = 256 / CG;
    constexpr int BM  = RG * RPT;     // 64
    constexpr int BK  = 16;
    static_assert(BM == 64, "tile geometry");
    __shared__ float xs[BK][BM];
    __shared__ float ws[BK][N];

    int tid = threadIdx.x;
    int cg = tid % CG, rg = tid / CG;
    int c0 = cg * CPT, r0 = rg * RPT;
    int brow = blockIdx.x * BM;

    float acc[RPT][CPT] = {};

    for (int k0 = 0; k0 < K; k0 += BK) {
        {
            int r = tid >> 2;
            int q = tid & 3;
            int row = brow + r;
            if (row >= M) row = M - 1;                 // clamp (stores guarded)
            const float4 xv = *(const float4*)(X + (size_t)row * K + k0 + q * 4);
            xs[q * 4 + 0][r] = xv.x;
            xs[q * 4 + 1][r] = xv.y;
            xs[q * 4 + 2][r] = xv.z;
            xs[q * 4 + 3][r] = xv.w;
        }
        {
            constexpr int NF4  = N / 4;
            constexpr int TOT4 = BK * NF4;
            #pragma unroll
            for (int t = 0; t < TOT4 / 256; ++t) {
                int idx = tid + t * 256;
                int kk = idx / NF4, n4 = idx % NF4;
                *(float4*)&ws[kk][n4 * 4] =
                    *(const float4*)(W + (size_t)(k0 + kk) * N + n4 * 4);
            }
        }
        __syncthreads();
        #pragma unroll
        for (int k = 0; k < BK; ++k) {
            float a[RPT], b[CPT];
            #pragma unroll
            for (int r = 0; r < RPT; ++r) a[r] = xs[k][r0 + r];
            #pragma unroll
            for (int c = 0; c < CPT; ++c) b[c] = ws[k][c0 + c];
            #pragma unroll
            for (int r = 0; r < RPT; ++r)
                #pragma unroll
                for (int c = 0; c < CPT; ++c)
                    acc[r][c] = fmaf(a[r], b[c], acc[r][c]);
        }
        __syncthreads();
    }

    #pragma unroll
    for (int r = 0; r < RPT; ++r) {
        int row = brow + r0 + r;
        if (row < M) {
            float s = dinv[row];
            uint4 p;
            p.x = pack_bf16_2(acc[r][0] * s, acc[r][1] * s);
            p.y = pack_bf16_2(acc[r][2] * s, acc[r][3] * s);
            p.z = pack_bf16_2(acc[r][4] * s, acc[r][5] * s);
            p.w = pack_bf16_2(acc[r][6] * s, acc[r][7] * s);
            *(uint4*)(Gp + (size_t)row * (N / 2) + c0 / 2) = p;
        }
    }
}

// ---------- aggregate, F=128 (bf16 source rows of 64 uints), fp32 out ----------
__global__ __launch_bounds__(256) void aggregate128_kernel(const unsigned* __restrict__ G,
        const int* __restrict__ csr, const int* __restrict__ offs,
        const float* __restrict__ dinv, const float* __restrict__ bias,
        float* __restrict__ out, int n) {
    int wave = threadIdx.x >> 6, lane = threadIdx.x & 63;
    int node = blockIdx.x * 4 + wave;
    if (node >= n) return;
    int beg = offs[node], end = offs[node + 1];

    unsigned u = G[(size_t)node * 64 + lane];          // self loop
    float a0 = bflo(u), a1 = bfhi(u);
    int e = beg;
    for (; e + 4 <= end; e += 4) {                     // 4 rows in flight
        int s0 = csr[e], s1 = csr[e + 1], s2 = csr[e + 2], s3 = csr[e + 3];
        unsigned u0 = G[(size_t)s0 * 64 + lane];
        unsigned u1 = G[(size_t)s1 * 64 + lane];
        unsigned u2 = G[(size_t)s2 * 64 + lane];
        unsigned u3 = G[(size_t)s3 * 64 + lane];
        a0 += (bflo(u0) + bflo(u1)) + (bflo(u2) + bflo(u3));
        a1 += (bfhi(u0) + bfhi(u1)) + (bfhi(u2) + bfhi(u3));
    }
    for (; e < end; ++e) {
        unsigned u0 = G[(size_t)csr[e] * 64 + lane];
        a0 += bflo(u0);
        a1 += bfhi(u0);
    }
    float di = dinv[node];
    float2 r;
    r.x = fmaxf(fmaf(a0, di, bias[lane * 2 + 0]), 0.0f);
    r.y = fmaxf(fmaf(a1, di, bias[lane * 2 + 1]), 0.0f);
    ((float2*)(out + (size_t)node * 128))[lane] = r;
}

// ---------- aggregate, F=64 (bf16 rows of 32 uints), split-wave 2 edges/instr ----------
__global__ __launch_bounds__(256) void aggregate64_kernel(const unsigned* __restrict__ G,
        const int* __restrict__ csr, const int* __restrict__ offs,
        const float* __restrict__ dinv, const float* __restrict__ bias,
        float* __restrict__ out, int n) {
    int wave = threadIdx.x >> 6, lane = threadIdx.x & 63;
    int node = blockIdx.x * 4 + wave;
    if (node >= n) return;
    int beg = offs[node], end = offs[node + 1];
    int half = lane >> 5, col = lane & 31;

    float a0 = 0.0f, a1 = 0.0f;
    if (half == 0) {                                   // self loop on low half
        unsigned u = G[(size_t)node * 32 + col];
        a0 = bflo(u); a1 = bfhi(u);
    }
    int e = beg;
    for (; e + 4 <= end; e += 4) {                     // 4 edges/iter (2 per half)
        int sA = csr[e + half], sB = csr[e + 2 + half];
        unsigned uA = G[(size_t)sA * 32 + col];
        unsigned uB = G[(size_t)sB * 32 + col];
        a0 += bflo(uA) + bflo(uB);
        a1 += bfhi(uA) + bfhi(uB);
    }
    if (e + 2 <= end) {
        int sA = csr[e + half];
        unsigned uA = G[(size_t)sA * 32 + col];
        a0 += bflo(uA);
        a1 += bfhi(uA);
        e += 2;
    }
    if (e < end && half == 0) {                        // odd tail: low half only
        unsigned uA = G[(size_t)csr[e] * 32 + col];
        a0 += bflo(uA);
        a1 += bfhi(uA);
    }
    a0 += __shfl_down(a0, 32, 64);                     // fold high half into low
    a1 += __shfl_down(a1, 32, 64);
    if (half == 0) {
        float di = dinv[node];
        float2 r;
        r.x = fmaxf(fmaf(a0, di, bias[col * 2 + 0]), 0.0f);
        r.y = fmaxf(fmaf(a1, di, bias[col * 2 + 1]), 0.0f);
        ((float2*)(out + (size_t)node * 64))[col] = r;
    }
}

extern "C" void kernel_launch(void* const* d_in, const int* in_sizes, int n_in,
                              void* d_out, int out_size, void* d_ws, size_t ws_size,
                              hipStream_t stream) {
    const float* x  = (const float*)d_in[0];
    const float* W1 = (const float*)d_in[1];
    const float* b1 = (const float*)d_in[2];
    const float* W2 = (const float*)d_in[3];
    const float* b2 = (const float*)d_in[4];
    const int* edge = (const int*)d_in[5];

    const int IN = 256, H1 = 128;
    const int E = in_sizes[5] / 2;
    const int N = in_sizes[0] / IN;
    const int* srcp = edge;
    const int* dstp = edge + E;

    char* ws = (char*)d_ws;
    auto alignup = [](size_t v) { return (v + 255) & ~(size_t)255; };
    size_t off = 0;
    size_t degSz = alignup((size_t)N * 4);
    int*      deg    = (int*)(ws + off);      off += degSz;
    int*      cursor = (int*)(ws + off);      off += degSz;
    int*      offs   = (int*)(ws + off);      off += alignup(((size_t)N + 1) * 4);
    float*    dinv   = (float*)(ws + off);    off += degSz;
    int*      psum   = (int*)(ws + off);      off += alignup(64 * 4);
    int*      csr    = (int*)(ws + off);      off += alignup((size_t)E * 4);
    unsigned* g1     = (unsigned*)(ws + off); off += alignup((size_t)N * (H1 / 2) * 4);
    float*    h1     = (float*)(ws + off);    off += alignup((size_t)N * H1 * 4);
    unsigned* g2     = g1;                    // g1 dead after aggregate1

    hipMemsetAsync(deg, 0, 2 * degSz, stream);   // deg + cursor contiguous

    int egrid = (E + 255) / 256;
    if (egrid > 2048) egrid = 2048;
    int sb = (N + 4095) / 4096;                  // 25 for N=100000 (<=64 required)

    hist_kernel<<<egrid, 256, 0, stream>>>(dstp, deg, E);
    scan_partial_kernel<<<sb, 1024, 0, stream>>>(deg, psum, dinv, N);
    scan_base_kernel<<<1, 64, 0, stream>>>(psum, offs, sb, N);
    scan_local_kernel<<<sb, 1024, 0, stream>>>(deg, psum, offs, N);
    fill_kernel<<<egrid, 256, 0, stream>>>(srcp, dstp, offs, cursor, csr, E);

    int mgrid = (N + 63) / 64;
    int agrid = (N + 3) / 4;

    // layer 1
    gemm_scale_kernel<256, 128, 4><<<mgrid, 256, 0, stream>>>(x, W1, dinv, g1, N);
    aggregate128_kernel<<<agrid, 256, 0, stream>>>(g1, csr, offs, dinv, b1, h1, N);
    // layer 2
    gemm_scale_kernel<128, 64, 2><<<mgrid, 256, 0, stream>>>(h1, W2, dinv, g2, N);
    aggregate64_kernel<<<agrid, 256, 0, stream>>>(g2, csr, offs, dinv, b2,
                                                  (float*)d_out, N);
}